// Round 14
// baseline (1257.073 us; speedup 1.0000x reference)
//
#include <hip/hip_runtime.h>

#define NN 20000     // nodes per graph
#define NE 320000    // edges per graph
#define NB 2         // graphs
#define HDIM 256     // hidden
#define NDIM 64      // node feature dim
#define EDIM 32      // edge feature dim
#define NL 4         // layers
#define CHUNK 16     // positions per edge-agg inner chunk (R8/R11-proven)

typedef short short8 __attribute__((ext_vector_type(8)));
typedef float f32x4 __attribute__((ext_vector_type(4)));

// gelu(x) = x - x/(e+1),  e = exp2(2.3022082*(x+0.044715x^3))
__device__ __forceinline__ float gelu_af(float x) {
    float x3 = x * x * x;
    float e = exp2f(2.3022082f * fmaf(0.044715f, x3, x));
    return fmaf(-x, __builtin_amdgcn_rcpf(e + 1.0f), x);
}

__device__ __forceinline__ unsigned short f2bf(float f) {
    unsigned int x = __float_as_uint(f);
    unsigned int r = (x + 0x7fffu + ((x >> 16) & 1u)) >> 16;
    return (unsigned short)r;
}
__device__ __forceinline__ float bf2f(unsigned short h) {
    return __uint_as_float(((unsigned int)h) << 16);
}

// ---------------- weight transpose + bf16 convert (once per launch) ---------
__global__ __launch_bounds__(256) void tr_k(
    const float* __restrict__ inW, const float* __restrict__ mW1,
    const float* __restrict__ mW2, const float* __restrict__ uW1,
    const float* __restrict__ uW2, const float* __restrict__ outW,
    unsigned short* __restrict__ dst)
{
    const int id = blockIdx.z;
    const float* src; int K, N; size_t doff;
    if (id == 0)       { src = inW;  K = 64;  N = 256; doff = 0; }
    else if (id <= 4)  { int l = id - 1;  src = mW1 + (size_t)l * 544 * 256; K = 544; N = 256; doff = 16384   + (size_t)l * 139264; }
    else if (id <= 8)  { int l = id - 5;  src = mW2 + (size_t)l * 256 * 256; K = 256; N = 256; doff = 573440  + (size_t)l * 65536;  }
    else if (id <= 12) { int l = id - 9;  src = uW1 + (size_t)l * 512 * 256; K = 512; N = 256; doff = 835584  + (size_t)l * 131072; }
    else if (id <= 16) { int l = id - 13; src = uW2 + (size_t)l * 256 * 256; K = 256; N = 256; doff = 1359872 + (size_t)l * 65536;  }
    else               { src = outW; K = 256; N = 64;  doff = 1622016; }

    const int k0 = blockIdx.x * 32, n0 = blockIdx.y * 32;
    if (k0 >= K || n0 >= N) return;   // block-uniform

    __shared__ float tile[32][33];
    const int tx = threadIdx.x & 31, ty = threadIdx.x >> 5;
    #pragma unroll
    for (int i = 0; i < 4; ++i) {
        int k = k0 + ty + i * 8, n = n0 + tx;
        tile[ty + i * 8][tx] = (k < K && n < N) ? src[(size_t)k * N + n] : 0.f;
    }
    __syncthreads();
    #pragma unroll
    for (int i = 0; i < 4; ++i) {
        int n = n0 + ty + i * 8, k = k0 + tx;
        if (n < N && k < K) dst[doff + (size_t)n * K + k] = f2bf(tile[tx][ty + i * 8]);
    }
}

// ---------------- W2@V1b precompute: WT[n][k] = sum_j W2[k][j] V1b[j][n] ----
__global__ __launch_bounds__(256) void wv_k(
    const float* __restrict__ mW2, const float* __restrict__ uW1,
    unsigned short* __restrict__ w2v1bT)
{
    const int l = blockIdx.z;
    const float* W2  = mW2 + (size_t)l * 65536;
    const float* V1b = uW1 + (size_t)l * 131072 + 65536;
    const int n0 = blockIdx.x * 16, k0 = blockIdx.y * 16;
    const int tx = threadIdx.x & 15, ty = threadIdx.x >> 4;
    __shared__ float sW[16][17], sV[16][17];
    float acc = 0.f;
    for (int j0 = 0; j0 < 256; j0 += 16) {
        sW[ty][tx] = W2[(size_t)(k0 + ty) * 256 + j0 + tx];
        sV[ty][tx] = V1b[(size_t)(j0 + ty) * 256 + n0 + tx];
        __syncthreads();
        #pragma unroll
        for (int jj = 0; jj < 16; ++jj)
            acc = fmaf(sW[ty][jj], sV[jj][tx], acc);
        __syncthreads();
    }
    w2v1bT[(size_t)l * 65536 + (size_t)(n0 + tx) * 256 + (k0 + ty)] = f2bf(acc);
}

// ---------------- b2@V1b + fused bias512 build ------------------------------
__global__ void bv_k(const float* __restrict__ mb1, const float* __restrict__ mb2,
                     const float* __restrict__ uW1,
                     float* __restrict__ b2v, float* __restrict__ bias512)
{
    const int l = blockIdx.x, t = threadIdx.x;   // 512 threads
    if (t < 256) {
        const float* V1b = uW1 + (size_t)l * 131072 + 65536;
        const float* b2  = mb2 + l * 256;
        float s = 0.f;
        for (int j = 0; j < 256; ++j) s = fmaf(b2[j], V1b[(size_t)j * 256 + t], s);
        b2v[l * 256 + t] = s;
    }
    bias512[l * 512 + t] = (t < 256) ? 0.f : mb1[l * 256 + (t - 256)];
}

// ---------------- MFMA GEMM v1 (64x128 tile) — used for In / Out ------------
// ASPLIT=0: A f32, runtime split (2 MFMA).  ASPLIT=1: pre-split planes (2 MFMA).
// CSPLIT=0: C f32.  CSPLIT=1: C hi/lo planes.
// MODE 0: C = A@W + bias(optional)
template <int MODE, int ASPLIT, int CSPLIT>
__global__ __launch_bounds__(256) void mgemm_k(
    const float* __restrict__ A,
    const unsigned short* __restrict__ Ah, const unsigned short* __restrict__ Al,
    const unsigned short* __restrict__ BT, int ldb,
    const float* __restrict__ bias,
    float* __restrict__ C, unsigned short* __restrict__ Ch, unsigned short* __restrict__ Cl,
    int M, int N, int K)
{
    __shared__ unsigned char smem[64 * 80 * 2 + 128 * 80];
    unsigned char* ahi = smem;
    unsigned char* alo = smem + 64 * 80;
    unsigned char* btl = smem + 64 * 80 * 2;

    const int tid = threadIdx.x;
    const int bm = blockIdx.x * 64;
    const int bn = blockIdx.y * 128;
    const int w = tid >> 6, lane = tid & 63;
    const int wr = w >> 1, wc = w & 1;
    const int lrow = lane & 15, lg = lane >> 4;

    f32x4 acc[2][4];
    #pragma unroll
    for (int i = 0; i < 2; ++i)
        #pragma unroll
        for (int j = 0; j < 4; ++j) acc[i][j] = (f32x4){0.f, 0.f, 0.f, 0.f};

    const int t1 = K >> 5;
    for (int t = 0; t < t1; ++t) {
        const int k0 = t * 32;
        {   // stage A
            const int row = tid >> 2, kq = (tid & 3) * 8;
            const int m = bm + row;
            if (ASPLIT == 1) {
                uint4 hv = make_uint4(0u, 0u, 0u, 0u), lv = hv;
                if (m < M) {
                    hv = *(const uint4*)&Ah[(size_t)m * K + k0 + kq];
                    lv = *(const uint4*)&Al[(size_t)m * K + k0 + kq];
                }
                *(uint4*)(ahi + row * 80 + kq * 2) = hv;
                *(uint4*)(alo + row * 80 + kq * 2) = lv;
            } else {
                float4 v0 = make_float4(0.f, 0.f, 0.f, 0.f), v1 = v0;
                if (m < M) {
                    v0 = *(const float4*)&A[(size_t)m * K + k0 + kq];
                    v1 = *(const float4*)&A[(size_t)m * K + k0 + kq + 4];
                }
                float vv[8] = {v0.x, v0.y, v0.z, v0.w, v1.x, v1.y, v1.z, v1.w};
                unsigned short hh[8], ll[8];
                #pragma unroll
                for (int j = 0; j < 8; ++j) {
                    hh[j] = f2bf(vv[j]);
                    ll[j] = f2bf(vv[j] - bf2f(hh[j]));
                }
                ushort4 ph0 = {hh[0], hh[1], hh[2], hh[3]}, ph1 = {hh[4], hh[5], hh[6], hh[7]};
                ushort4 pl0 = {ll[0], ll[1], ll[2], ll[3]}, pl1 = {ll[4], ll[5], ll[6], ll[7]};
                *(ushort4*)(ahi + row * 80 + kq * 2)     = ph0;
                *(ushort4*)(ahi + row * 80 + kq * 2 + 8) = ph1;
                *(ushort4*)(alo + row * 80 + kq * 2)     = pl0;
                *(ushort4*)(alo + row * 80 + kq * 2 + 8) = pl1;
            }
        }
        {   // stage B
            const int row = tid >> 1, half = tid & 1;
            const int n = bn + row;
            #pragma unroll
            for (int c = 0; c < 2; ++c) {
                const int q = half * 2 + c;
                uint4 d = make_uint4(0u, 0u, 0u, 0u);
                if (n < N) d = *(const uint4*)&BT[(size_t)n * ldb + k0 + q * 8];
                *(uint4*)(btl + row * 80 + q * 16) = d;
            }
        }
        __syncthreads();

        short8 ah[2], al[2], bfr[4];
        #pragma unroll
        for (int mi = 0; mi < 2; ++mi) {
            const int r = wr * 32 + mi * 16 + lrow;
            ah[mi] = *(const short8*)(ahi + r * 80 + lg * 16);
            al[mi] = *(const short8*)(alo + r * 80 + lg * 16);
        }
        #pragma unroll
        for (int ni = 0; ni < 4; ++ni) {
            const int r = wc * 64 + ni * 16 + lrow;
            bfr[ni] = *(const short8*)(btl + r * 80 + lg * 16);
        }
        #pragma unroll
        for (int mi = 0; mi < 2; ++mi)
            #pragma unroll
            for (int ni = 0; ni < 4; ++ni) {
                acc[mi][ni] = __builtin_amdgcn_mfma_f32_16x16x32_bf16(ah[mi], bfr[ni], acc[mi][ni], 0, 0, 0);
                acc[mi][ni] = __builtin_amdgcn_mfma_f32_16x16x32_bf16(al[mi], bfr[ni], acc[mi][ni], 0, 0, 0);
            }
        __syncthreads();
    }

    #pragma unroll
    for (int mi = 0; mi < 2; ++mi) {
        #pragma unroll
        for (int ni = 0; ni < 4; ++ni) {
            const int ncol = bn + wc * 64 + ni * 16 + lrow;
            if (ncol >= N) continue;
            const float bv = bias ? bias[ncol] : 0.f;
            const int mbase = bm + wr * 32 + mi * 16 + lg * 4;
            #pragma unroll
            for (int r = 0; r < 4; ++r) {
                const int m = mbase + r;
                if (m >= M) continue;
                const size_t cb = (size_t)m * N + ncol;
                float v = acc[mi][ni][r] + bv;
                if (CSPLIT == 1) {
                    unsigned short hi = f2bf(v);
                    unsigned short lo = f2bf(v - bf2f(hi));
                    Ch[cb] = hi; Cl[cb] = lo;
                } else {
                    C[cb] = v;
                }
            }
        }
    }
}

// ---------------- MFMA GEMM v2 (128x128 tile, single-plane bf16 A) ----------
// 4 waves 2x2, 64x64 per wave, 16 MFMA per K-step per wave.
// MODE 0: C = A@W + bias          MODE 3: C = (Chi+Clo) + A@W + bias
// MODE 4: C = gelu(A@W + A2@W2 + degf[m]*bias2 + bias)
// CSPLIT=1: C hi/lo planes.  CSPLIT=2: C bf16 single.
template <int MODE, int CSPLIT>
__global__ __launch_bounds__(256) void mgemm2_k(
    const unsigned short* __restrict__ Ah, const unsigned short* __restrict__ BT, int ldb,
    const unsigned short* __restrict__ A2h, const unsigned short* __restrict__ BT2, int ldb2,
    const float* __restrict__ bias, const float* __restrict__ bias2,
    const float* __restrict__ degf,
    unsigned short* __restrict__ Ch, unsigned short* __restrict__ Cl,
    int M, int N, int K, int K2, int bkoff)
{
    __shared__ unsigned char smem[128 * 80 * 2];   // A,B tiles (80B rows)
    unsigned char* abuf = smem;
    unsigned char* bbuf = smem + 128 * 80;

    const int tid = threadIdx.x;
    const int bm = blockIdx.x * 128;
    const int bn = blockIdx.y * 128;
    const int w = tid >> 6, lane = tid & 63;
    const int wr = w >> 1, wc = w & 1;
    const int lrow = lane & 15, lg = lane >> 4;

    f32x4 acc[4][4];
    #pragma unroll
    for (int i = 0; i < 4; ++i)
        #pragma unroll
        for (int j = 0; j < 4; ++j) acc[i][j] = (f32x4){0.f, 0.f, 0.f, 0.f};

    const int t1 = K >> 5, t2 = K2 >> 5;
    for (int t = 0; t < t1 + t2; ++t) {
        int k0, lda, ldbv;
        const unsigned short* Ap; const unsigned short* Bp;
        if (t < t1) { Ap = Ah;  Bp = BT;  k0 = t * 32;        lda = K;  ldbv = ldb;  }
        else        { Ap = A2h; Bp = BT2; k0 = (t - t1) * 32; lda = K2; ldbv = ldb2; }

        {   // stage A: 128 rows x 32 k bf16; thread = (row, half-row 32B)
            const int row = tid >> 1, sg = (tid & 1) * 16;   // shorts offset
            const int m = bm + row;
            uint4 d0 = make_uint4(0u, 0u, 0u, 0u), d1 = d0;
            if (m < M) {
                d0 = *(const uint4*)&Ap[(size_t)m * lda + k0 + sg];
                d1 = *(const uint4*)&Ap[(size_t)m * lda + k0 + sg + 8];
            }
            *(uint4*)(abuf + row * 80 + sg * 2)      = d0;
            *(uint4*)(abuf + row * 80 + sg * 2 + 16) = d1;
        }
        {   // stage B: 128 n-rows x 32 k bf16; fused-B via (n>>8)*bkoff shift
            const int row = tid >> 1, sg = (tid & 1) * 16;
            const int n = bn + row;
            const unsigned short* brow = Bp + (size_t)(n & 255) * ldbv + (n >> 8) * bkoff;
            uint4 d0 = make_uint4(0u, 0u, 0u, 0u), d1 = d0;
            if (n < N) {
                d0 = *(const uint4*)&brow[k0 + sg];
                d1 = *(const uint4*)&brow[k0 + sg + 8];
            }
            *(uint4*)(bbuf + row * 80 + sg * 2)      = d0;
            *(uint4*)(bbuf + row * 80 + sg * 2 + 16) = d1;
        }
        __syncthreads();

        short8 ah[4], bfr[4];
        #pragma unroll
        for (int mi = 0; mi < 4; ++mi)
            ah[mi] = *(const short8*)(abuf + (wr * 64 + mi * 16 + lrow) * 80 + lg * 16);
        #pragma unroll
        for (int ni = 0; ni < 4; ++ni)
            bfr[ni] = *(const short8*)(bbuf + (wc * 64 + ni * 16 + lrow) * 80 + lg * 16);
        #pragma unroll
        for (int mi = 0; mi < 4; ++mi)
            #pragma unroll
            for (int ni = 0; ni < 4; ++ni)
                acc[mi][ni] = __builtin_amdgcn_mfma_f32_16x16x32_bf16(ah[mi], bfr[ni], acc[mi][ni], 0, 0, 0);
        __syncthreads();
    }

    // epilogue: D row = 4*lg + reg, col = lrow
    #pragma unroll
    for (int mi = 0; mi < 4; ++mi) {
        #pragma unroll
        for (int ni = 0; ni < 4; ++ni) {
            const int ncol = bn + wc * 64 + ni * 16 + lrow;
            if (ncol >= N) continue;
            const float bv = bias ? bias[ncol] : 0.f;
            const float b2vv = (MODE == 4) ? bias2[ncol] : 0.f;
            const int mbase = bm + wr * 64 + mi * 16 + lg * 4;
            #pragma unroll
            for (int r = 0; r < 4; ++r) {
                const int m = mbase + r;
                if (m >= M) continue;
                const size_t cb = (size_t)m * N + ncol;
                float v = acc[mi][ni][r];
                if (MODE == 0)      v += bv;
                else if (MODE == 3) v += bf2f(Ch[cb]) + bf2f(Cl[cb]) + bv;
                else                v = gelu_af(v + degf[m] * b2vv + bv);
                if (CSPLIT == 1) {
                    unsigned short hi = f2bf(v);
                    unsigned short lo = f2bf(v - bf2f(hi));
                    Ch[cb] = hi; Cl[cb] = lo;
                } else {
                    Ch[cb] = f2bf(v);
                }
            }
        }
    }
}

// ---------------- CSR build (counting sort by destination), batched ---------
__global__ void hist2_k(const int* __restrict__ ei, int* __restrict__ cnt) {
    int i = blockIdx.x * blockDim.x + threadIdx.x;
    if (i < NB * NE) {
        const int g = i / NE, e = i - g * NE;
        atomicAdd(&cnt[g * NN + ei[(size_t)g * NE * 2 + 2 * e + 1]], 1);
    }
}

__global__ void scan2_k(const int* __restrict__ cnt_all, int* __restrict__ row_ptr_all,
                        int* __restrict__ cursor_all, float* __restrict__ degf_all) {
    const int g = blockIdx.x;
    const int* cnt = cnt_all + g * NN;
    int* row_ptr = row_ptr_all + g * (NN + 1);
    int* cursor  = cursor_all + g * NN;
    float* degf  = degf_all + g * NN;
    __shared__ int part[256];
    int tid = threadIdx.x;
    const int per = (NN + 255) >> 8;
    int s0 = tid * per;
    int s1 = s0 + per; if (s1 > NN) s1 = NN; if (s0 > NN) s0 = NN;
    int sum = 0;
    for (int i = s0; i < s1; ++i) sum += cnt[i];
    part[tid] = sum;
    __syncthreads();
    if (tid == 0) {
        int r = 0;
        for (int i = 0; i < 256; ++i) { int v = part[i]; part[i] = r; r += v; }
    }
    __syncthreads();
    int off = part[tid];
    for (int i = s0; i < s1; ++i) {
        int c = cnt[i];
        row_ptr[i] = off; cursor[i] = off; degf[i] = (float)c;
        off += c;
    }
    if (tid == 255) row_ptr[NN] = off;
}

__global__ void fill2_k(const int* __restrict__ ei, int* __restrict__ cursor,
                        int2* __restrict__ csr_pack) {
    int i = blockIdx.x * blockDim.x + threadIdx.x;
    if (i < NB * NE) {
        const int g = i / NE, e = i - g * NE;
        const int* eig = ei + (size_t)g * NE * 2;
        int s = eig[2 * e + 0];
        int d = eig[2 * e + 1];
        int pos = atomicAdd(&cursor[g * NN + d], 1);
        csr_pack[(size_t)g * NE + pos] = make_int2(s, e);
    }
}

// ---------------- Edge aggregation v10: 1-wave blocks, bf16 T12 -------------
// Per-wave logic identical to v9 but 64-thread blocks: 8.3KB LDS/block ->
// ~19 blocks/CU resident, finest-grain degree-imbalance.
__global__ __launch_bounds__(64) void edge_agg10_k(
    const unsigned short* __restrict__ T12b,  // [g][NN][512] bf16
    const float* __restrict__ efeat,
    const unsigned short* __restrict__ w1t,   // [256][544] bf16, W1c at col 512
    const int2* __restrict__ csr_pack, const int* __restrict__ row_ptr,
    unsigned short* __restrict__ Shi)
{
    __shared__ unsigned short efo[CHUNK * 260];   // 8320 B

    const int g   = blockIdx.x / NN;
    const int d   = blockIdx.x % NN;
    const int lane = threadIdx.x & 63;
    const int lrow = lane & 15, lg = lane >> 4;

    const unsigned short* T12g = T12b + (size_t)g * NN * 512;
    const float* efg  = efeat + (size_t)g * NE * EDIM;
    const int2* cpG   = csr_pack + (size_t)g * NE;
    const int* rpG    = row_ptr + (size_t)g * (NN + 1);

    const int dstart = rpG[d], dend = rpG[d + 1];
    const int c0 = lane * 4;
    const char* tb = (const char*)T12g;   // row stride 1024B (512 bf16)

    // W1c^T B-fragments in registers: tile ni covers cols ni*16+lrow
    short8 bfrag[16];
    #pragma unroll
    for (int ni = 0; ni < 16; ++ni)
        bfrag[ni] = *(const short8*)&w1t[(size_t)(ni * 16 + lrow) * 544 + 512 + lg * 8];

    const ushort4 hdu = *(const ushort4*)(tb + (unsigned)d * 1024u + 512u + (unsigned)c0 * 2u);
    const float4 hd = make_float4(bf2f(hdu.x), bf2f(hdu.y), bf2f(hdu.z), bf2f(hdu.w));
    float4 acc = make_float4(0.f, 0.f, 0.f, 0.f);

    for (int P = dstart; P < dend; P += CHUNK) {
        const int nv = dend - P < CHUNK ? dend - P : CHUNK;
        int pos = P + lrow; if (pos >= dend) pos = dend - 1;

        const int2 cp = cpG[pos];
        const int myid = cp.x, eid = cp.y;

        // A fragment: row lrow = position, k = lg*8..+7 (bf16 from global)
        const float* er = &efg[(size_t)eid * EDIM + lg * 8];
        float4 v0 = *(const float4*)er;
        float4 v1 = *(const float4*)(er + 4);
        short8 af;
        af[0] = (short)f2bf(v0.x); af[1] = (short)f2bf(v0.y);
        af[2] = (short)f2bf(v0.z); af[3] = (short)f2bf(v0.w);
        af[4] = (short)f2bf(v1.x); af[5] = (short)f2bf(v1.y);
        af[6] = (short)f2bf(v1.z); af[7] = (short)f2bf(v1.w);

        // 16 MFMAs -> Ef chunk in LDS (D: row=4lg+r, col=ni*16+lrow)
        #pragma unroll
        for (int ni = 0; ni < 16; ++ni) {
            f32x4 a4 = (f32x4){0.f, 0.f, 0.f, 0.f};
            a4 = __builtin_amdgcn_mfma_f32_16x16x32_bf16(af, bfrag[ni], a4, 0, 0, 0);
            #pragma unroll
            for (int r = 0; r < 4; ++r)
                efo[(4 * lg + r) * 260 + ni * 16 + lrow] = f2bf(a4[r]);
        }

        // consume nv positions, 4-wide gather ILP (same-wave LDS, no barrier)
        for (int p = P; p < P + nv; p += 4) {
            const int nc = P + nv - p;
            int sj[4]; ushort4 hsu[4]; ushort4 ef4[4];
            #pragma unroll
            for (int j = 0; j < 4; ++j) {
                const int q = p + ((j < nc) ? j : 0);
                sj[j] = __shfl(myid, q - P, 64);
            }
            #pragma unroll
            for (int j = 0; j < 4; ++j) {
                const int q = p + ((j < nc) ? j : 0);
                hsu[j] = *(const ushort4*)(tb + (unsigned)sj[j] * 1024u + (unsigned)c0 * 2u);
                ef4[j] = *(const ushort4*)&efo[(q - P) * 260 + c0];
            }
            #pragma unroll
            for (int j = 0; j < 4; ++j) {
                if (j < nc) {   // wave-uniform predicate
                    acc.x += gelu_af(bf2f(hsu[j].x) + hd.x + bf2f(ef4[j].x));
                    acc.y += gelu_af(bf2f(hsu[j].y) + hd.y + bf2f(ef4[j].y));
                    acc.z += gelu_af(bf2f(hsu[j].z) + hd.z + bf2f(ef4[j].z));
                    acc.w += gelu_af(bf2f(hsu[j].w) + hd.w + bf2f(ef4[j].w));
                }
            }
        }
    }

    ushort4 ho;
    ho.x = f2bf(acc.x); ho.y = f2bf(acc.y);
    ho.z = f2bf(acc.z); ho.w = f2bf(acc.w);
    *(ushort4*)&Shi[((size_t)g * NN + d) * HDIM + c0] = ho;
}

// ---------------- launcher ---------------------------------------------------
extern "C" void kernel_launch(void* const* d_in, const int* in_sizes, int n_in,
                              void* d_out, int out_size, void* d_ws, size_t ws_size,
                              hipStream_t stream)
{
    const float* nf    = (const float*)d_in[0];
    const int*   ei    = (const int*)  d_in[1];
    const float* efeat = (const float*)d_in[2];
    const float* inW   = (const float*)d_in[3];
    const float* inb   = (const float*)d_in[4];
    const float* mW1   = (const float*)d_in[5];
    const float* mb1   = (const float*)d_in[6];
    const float* mW2   = (const float*)d_in[7];
    const float* mb2   = (const float*)d_in[8];
    const float* uW1   = (const float*)d_in[9];
    const float* ub1   = (const float*)d_in[10];
    const float* uW2   = (const float*)d_in[11];
    const float* ub2   = (const float*)d_in[12];
    const float* outW  = (const float*)d_in[13];
    const float* outb  = (const float*)d_in[14];
    float* outp = (float*)d_out;

    const int MT = NB * NN;   // 40000 batched rows

    char* p = (char*)d_ws;
    auto carve = [&](size_t bytes) -> void* {
        void* r = (void*)p;
        p += (bytes + 255) & ~(size_t)255;
        return r;
    };
    unsigned short* hS  = (unsigned short*)carve((size_t)2 * MT * HDIM * 2);  // hi|lo planes
    unsigned short* T3S = (unsigned short*)carve((size_t)MT * HDIM * 2);      // Sagg single bf16
    unsigned short* T12b = (unsigned short*)carve((size_t)MT * 512 * 2);  // Hs|Hd bf16 (41 MB)
    unsigned short* US = T12b;              // alias: U (single plane) reuses dead T12
    int2* csr_pack = (int2*)carve((size_t)NB * NE * 8);
    int* row_ptr = (int*)carve((size_t)NB * (NN + 1) * 4);
    int* cursor  = (int*)carve((size_t)NB * NN * 4);
    int* cnt     = (int*)carve((size_t)NB * NN * 4);
    float* degf  = (float*)carve((size_t)MT * 4);
    unsigned short* wtbuf  = (unsigned short*)carve((size_t)1638400 * 2);
    unsigned short* w2v1bT = (unsigned short*)carve((size_t)4 * 65536 * 2);
    float* b2v     = (float*)carve((size_t)4 * 256 * 4);
    float* bias512 = (float*)carve((size_t)4 * 512 * 4);
    (void)ws_size; (void)in_sizes; (void)n_in; (void)out_size;

    unsigned short* hHi  = hS;   unsigned short* hLo  = hS  + (size_t)MT * HDIM;
    unsigned short* t3S  = T3S;  // single plane
    unsigned short* uS   = US;   // single plane

    const dim3 blk(256);
    const dim3 gIn(625, 2), gOut(625, 1);              // v1 64x128 tiles
    const dim3 gHsHd(313, 4), gU(313, 2), gRes(313, 2); // v2 128x128 tiles
    const dim3 gE(NB * NN);    // 40000 one-wave blocks
    const dim3 blkE(64);

    // once: weight transforms
    tr_k<<<dim3(17, 8, 18), blk, 0, stream>>>(inW, mW1, mW2, uW1, uW2, outW, wtbuf);
    wv_k<<<dim3(16, 16, 4), blk, 0, stream>>>(mW2, uW1, w2v1bT);
    bv_k<<<dim3(4), dim3(512), 0, stream>>>(mb1, mb2, uW1, b2v, bias512);

    const unsigned short* wtIn  = wtbuf;
    const unsigned short* wtW1  = wtbuf + 16384;
    const unsigned short* wtU1  = wtbuf + 835584;
    const unsigned short* wtU2  = wtbuf + 1359872;
    const unsigned short* wtOut = wtbuf + 1622016;

    // CSR for both graphs (batched)
    hipMemsetAsync(cnt, 0, (size_t)NB * NN * sizeof(int), stream);
    hist2_k<<<(NB * NE + 255) / 256, blk, 0, stream>>>(ei, cnt);
    scan2_k<<<dim3(NB), blk, 0, stream>>>(cnt, row_ptr, cursor, degf);
    fill2_k<<<(NB * NE + 255) / 256, blk, 0, stream>>>(ei, cursor, csr_pack);

    // h = nf @ in_W + in_b  (batched M=40000) -> split planes
    mgemm_k<0, 0, 1><<<gIn, blk, 0, stream>>>(
        nf, nullptr, nullptr, wtIn, NDIM,
        inb, nullptr, hHi, hLo, MT, HDIM, NDIM);

    for (int l = 0; l < NL; ++l) {
        const unsigned short* w1t = wtW1 + (size_t)l * 139264;
        const unsigned short* u1t = wtU1 + (size_t)l * 131072;
        const unsigned short* u2t = wtU2 + (size_t)l * 65536;

        // T12 = bf16(hHi @ [W1a|W1b] + [0,b1])   (128x128 tile)
        mgemm2_k<0, 2><<<gHsHd, blk, 0, stream>>>(
            hHi, w1t, 544,
            nullptr, nullptr, 0,
            bias512 + l * 512, nullptr, nullptr,
            T12b, nullptr, MT, 512, HDIM, 0, 256);

        // Sagg (fused Ef MFMA + aggregate, both graphs) -> t3S single bf16
        edge_agg10_k<<<gE, blkE, 0, stream>>>(T12b, efeat, w1t,
                                              csr_pack, row_ptr, t3S);

        // U = gelu(hHi@V1a + Sagg@(W2@V1b) + deg*(b2@V1b) + c1) -> uS single bf16
        mgemm2_k<4, 2><<<gU, blk, 0, stream>>>(
            hHi, u1t, 512,
            t3S, w2v1bT + (size_t)l * 65536, 256,
            ub1 + l * HDIM, b2v + l * 256, degf,
            uS, nullptr, MT, HDIM, HDIM, HDIM, 0);

        // h = h + U@V2 + c2  (U single plane) -> split planes
        mgemm2_k<3, 1><<<gRes, blk, 0, stream>>>(
            uS, u2t, HDIM,
            nullptr, nullptr, 0,
            ub2 + l * HDIM, nullptr, nullptr,
            hHi, hLo, MT, HDIM, HDIM, 0, 0);
    }

    // out = h @ out_W + out_b (f32, batched; split A for final accuracy)
    mgemm_k<0, 1, 0><<<gOut, blk, 0, stream>>>(
        nullptr, hHi, hLo, wtOut, HDIM,
        outb, outp, nullptr, nullptr, MT, NDIM, HDIM);
}

// Round 15
// 1189.294 us; speedup vs baseline: 1.0570x; 1.0570x over previous
//
#include <hip/hip_runtime.h>

#define NN 20000     // nodes per graph
#define NE 320000    // edges per graph
#define NB 2         // graphs
#define HDIM 256     // hidden
#define NDIM 64      // node feature dim
#define EDIM 32      // edge feature dim
#define NL 4         // layers
#define CHUNK 16     // positions per edge-agg inner chunk (R8/R11-proven)

typedef short short8 __attribute__((ext_vector_type(8)));
typedef float f32x4 __attribute__((ext_vector_type(4)));

// gelu(x) = x - x/(e+1),  e = exp2(2.3022082*(x+0.044715x^3))
__device__ __forceinline__ float gelu_af(float x) {
    float x3 = x * x * x;
    float e = exp2f(2.3022082f * fmaf(0.044715f, x3, x));
    return fmaf(-x, __builtin_amdgcn_rcpf(e + 1.0f), x);
}

__device__ __forceinline__ unsigned short f2bf(float f) {
    unsigned int x = __float_as_uint(f);
    unsigned int r = (x + 0x7fffu + ((x >> 16) & 1u)) >> 16;
    return (unsigned short)r;
}
__device__ __forceinline__ float bf2f(unsigned short h) {
    return __uint_as_float(((unsigned int)h) << 16);
}

// ---------------- weight transpose + bf16 convert (once per launch) ---------
__global__ __launch_bounds__(256) void tr_k(
    const float* __restrict__ inW, const float* __restrict__ mW1,
    const float* __restrict__ mW2, const float* __restrict__ uW1,
    const float* __restrict__ uW2, const float* __restrict__ outW,
    unsigned short* __restrict__ dst)
{
    const int id = blockIdx.z;
    const float* src; int K, N; size_t doff;
    if (id == 0)       { src = inW;  K = 64;  N = 256; doff = 0; }
    else if (id <= 4)  { int l = id - 1;  src = mW1 + (size_t)l * 544 * 256; K = 544; N = 256; doff = 16384   + (size_t)l * 139264; }
    else if (id <= 8)  { int l = id - 5;  src = mW2 + (size_t)l * 256 * 256; K = 256; N = 256; doff = 573440  + (size_t)l * 65536;  }
    else if (id <= 12) { int l = id - 9;  src = uW1 + (size_t)l * 512 * 256; K = 512; N = 256; doff = 835584  + (size_t)l * 131072; }
    else if (id <= 16) { int l = id - 13; src = uW2 + (size_t)l * 256 * 256; K = 256; N = 256; doff = 1359872 + (size_t)l * 65536;  }
    else               { src = outW; K = 256; N = 64;  doff = 1622016; }

    const int k0 = blockIdx.x * 32, n0 = blockIdx.y * 32;
    if (k0 >= K || n0 >= N) return;   // block-uniform

    __shared__ float tile[32][33];
    const int tx = threadIdx.x & 31, ty = threadIdx.x >> 5;
    #pragma unroll
    for (int i = 0; i < 4; ++i) {
        int k = k0 + ty + i * 8, n = n0 + tx;
        tile[ty + i * 8][tx] = (k < K && n < N) ? src[(size_t)k * N + n] : 0.f;
    }
    __syncthreads();
    #pragma unroll
    for (int i = 0; i < 4; ++i) {
        int n = n0 + ty + i * 8, k = k0 + tx;
        if (n < N && k < K) dst[doff + (size_t)n * K + k] = f2bf(tile[tx][ty + i * 8]);
    }
}

// ---------------- W2@V1b precompute: WT[n][k] = sum_j W2[k][j] V1b[j][n] ----
__global__ __launch_bounds__(256) void wv_k(
    const float* __restrict__ mW2, const float* __restrict__ uW1,
    unsigned short* __restrict__ w2v1bT)
{
    const int l = blockIdx.z;
    const float* W2  = mW2 + (size_t)l * 65536;
    const float* V1b = uW1 + (size_t)l * 131072 + 65536;
    const int n0 = blockIdx.x * 16, k0 = blockIdx.y * 16;
    const int tx = threadIdx.x & 15, ty = threadIdx.x >> 4;
    __shared__ float sW[16][17], sV[16][17];
    float acc = 0.f;
    for (int j0 = 0; j0 < 256; j0 += 16) {
        sW[ty][tx] = W2[(size_t)(k0 + ty) * 256 + j0 + tx];
        sV[ty][tx] = V1b[(size_t)(j0 + ty) * 256 + n0 + tx];
        __syncthreads();
        #pragma unroll
        for (int jj = 0; jj < 16; ++jj)
            acc = fmaf(sW[ty][jj], sV[jj][tx], acc);
        __syncthreads();
    }
    w2v1bT[(size_t)l * 65536 + (size_t)(n0 + tx) * 256 + (k0 + ty)] = f2bf(acc);
}

// ---------------- b2@V1b + fused bias512 build ------------------------------
__global__ void bv_k(const float* __restrict__ mb1, const float* __restrict__ mb2,
                     const float* __restrict__ uW1,
                     float* __restrict__ b2v, float* __restrict__ bias512)
{
    const int l = blockIdx.x, t = threadIdx.x;   // 512 threads
    if (t < 256) {
        const float* V1b = uW1 + (size_t)l * 131072 + 65536;
        const float* b2  = mb2 + l * 256;
        float s = 0.f;
        for (int j = 0; j < 256; ++j) s = fmaf(b2[j], V1b[(size_t)j * 256 + t], s);
        b2v[l * 256 + t] = s;
    }
    bias512[l * 512 + t] = (t < 256) ? 0.f : mb1[l * 256 + (t - 256)];
}

// ---------------- MFMA GEMM ------------------------------------------------
// ASPLIT=0: A f32, runtime split (2 MFMA).  ASPLIT=1: pre-split planes (2 MFMA).
// ASPLIT=2: A (and A2) single bf16 plane (1 MFMA per fragment).
// CSPLIT=0: C f32.  CSPLIT=1: C hi/lo planes.  CSPLIT=2: C bf16 single.
// MODE 0: C = A@W + bias(optional)
// MODE 3: C = (Chi+Clo) + A@W + bias      (residual; A != C buffers)
// MODE 4: C = gelu(A@W + A2@W2 + degf[m]*bias2 + bias)
template <int MODE, int ASPLIT, int CSPLIT>
__global__ __launch_bounds__(256) void mgemm_k(
    const float* __restrict__ A,
    const unsigned short* __restrict__ Ah, const unsigned short* __restrict__ Al,
    const unsigned short* __restrict__ BT, int ldb,
    const unsigned short* __restrict__ A2h, const unsigned short* __restrict__ A2l,
    const unsigned short* __restrict__ BT2, int ldb2,
    const float* __restrict__ bias, const float* __restrict__ bias2,
    const float* __restrict__ degf,
    float* __restrict__ C, unsigned short* __restrict__ Ch, unsigned short* __restrict__ Cl,
    int M, int N, int K, int K2, int bkoff)
{
    __shared__ unsigned char smem[64 * 80 * 2 + 128 * 80];  // ahi, alo, bt (80B rows)
    unsigned char* ahi = smem;
    unsigned char* alo = smem + 64 * 80;
    unsigned char* btl = smem + 64 * 80 * 2;

    const int tid = threadIdx.x;
    const int bm = blockIdx.x * 64;
    const int bn = blockIdx.y * 128;
    const int w = tid >> 6, lane = tid & 63;
    const int wr = w >> 1, wc = w & 1;
    const int lrow = lane & 15, lg = lane >> 4;

    f32x4 acc[2][4];
    #pragma unroll
    for (int i = 0; i < 2; ++i)
        #pragma unroll
        for (int j = 0; j < 4; ++j) acc[i][j] = (f32x4){0.f, 0.f, 0.f, 0.f};

    const int t1 = K >> 5, t2 = K2 >> 5;
    for (int t = 0; t < t1 + t2; ++t) {
        int k0, lda, ldbv;
        const float* Ap; const unsigned short* Ahp; const unsigned short* Alp;
        const unsigned short* Bp;
        if (t < t1) { Ap = A;  Ahp = Ah;  Alp = Al;  Bp = BT;  k0 = t * 32;        lda = K;  ldbv = ldb;  }
        else        { Ap = nullptr; Ahp = A2h; Alp = A2l; Bp = BT2; k0 = (t - t1) * 32; lda = K2; ldbv = ldb2; }

        {   // stage A
            const int row = tid >> 2, kq = (tid & 3) * 8;
            const int m = bm + row;
            if (ASPLIT == 1) {
                uint4 hv = make_uint4(0u, 0u, 0u, 0u), lv = hv;
                if (m < M) {
                    hv = *(const uint4*)&Ahp[(size_t)m * lda + k0 + kq];
                    lv = *(const uint4*)&Alp[(size_t)m * lda + k0 + kq];
                }
                *(uint4*)(ahi + row * 80 + kq * 2) = hv;
                *(uint4*)(alo + row * 80 + kq * 2) = lv;
            } else if (ASPLIT == 2) {
                uint4 hv = make_uint4(0u, 0u, 0u, 0u);
                if (m < M) hv = *(const uint4*)&Ahp[(size_t)m * lda + k0 + kq];
                *(uint4*)(ahi + row * 80 + kq * 2) = hv;
            } else {
                float4 v0 = make_float4(0.f, 0.f, 0.f, 0.f), v1 = v0;
                if (m < M) {
                    v0 = *(const float4*)&Ap[(size_t)m * lda + k0 + kq];
                    v1 = *(const float4*)&Ap[(size_t)m * lda + k0 + kq + 4];
                }
                float vv[8] = {v0.x, v0.y, v0.z, v0.w, v1.x, v1.y, v1.z, v1.w};
                unsigned short hh[8], ll[8];
                #pragma unroll
                for (int j = 0; j < 8; ++j) {
                    hh[j] = f2bf(vv[j]);
                    ll[j] = f2bf(vv[j] - bf2f(hh[j]));
                }
                ushort4 ph0 = {hh[0], hh[1], hh[2], hh[3]}, ph1 = {hh[4], hh[5], hh[6], hh[7]};
                ushort4 pl0 = {ll[0], ll[1], ll[2], ll[3]}, pl1 = {ll[4], ll[5], ll[6], ll[7]};
                *(ushort4*)(ahi + row * 80 + kq * 2)     = ph0;
                *(ushort4*)(ahi + row * 80 + kq * 2 + 8) = ph1;
                *(ushort4*)(alo + row * 80 + kq * 2)     = pl0;
                *(ushort4*)(alo + row * 80 + kq * 2 + 8) = pl1;
            }
        }
        {   // stage B: 128 n-rows x 32 k bf16; fused-B via (n>>8)*bkoff column shift
            const int row = tid >> 1, half = tid & 1;
            const int n = bn + row;
            const unsigned short* brow = Bp + (size_t)(n & 255) * ldbv + (n >> 8) * bkoff;
            #pragma unroll
            for (int c = 0; c < 2; ++c) {
                const int q = half * 2 + c;
                uint4 d = make_uint4(0u, 0u, 0u, 0u);
                if (n < N) d = *(const uint4*)&brow[k0 + q * 8];
                *(uint4*)(btl + row * 80 + q * 16) = d;
            }
        }
        __syncthreads();

        short8 ah[2], al[2], bfr[4];
        #pragma unroll
        for (int mi = 0; mi < 2; ++mi) {
            const int r = wr * 32 + mi * 16 + lrow;
            ah[mi] = *(const short8*)(ahi + r * 80 + lg * 16);
            if (ASPLIT != 2) al[mi] = *(const short8*)(alo + r * 80 + lg * 16);
        }
        #pragma unroll
        for (int ni = 0; ni < 4; ++ni) {
            const int r = wc * 64 + ni * 16 + lrow;
            bfr[ni] = *(const short8*)(btl + r * 80 + lg * 16);
        }
        #pragma unroll
        for (int mi = 0; mi < 2; ++mi)
            #pragma unroll
            for (int ni = 0; ni < 4; ++ni) {
                acc[mi][ni] = __builtin_amdgcn_mfma_f32_16x16x32_bf16(ah[mi], bfr[ni], acc[mi][ni], 0, 0, 0);
                if (ASPLIT != 2)
                    acc[mi][ni] = __builtin_amdgcn_mfma_f32_16x16x32_bf16(al[mi], bfr[ni], acc[mi][ni], 0, 0, 0);
            }
        __syncthreads();
    }

    // epilogue: D row = 4*lg + reg, col = lrow
    #pragma unroll
    for (int mi = 0; mi < 2; ++mi) {
        #pragma unroll
        for (int ni = 0; ni < 4; ++ni) {
            const int ncol = bn + wc * 64 + ni * 16 + lrow;
            if (ncol >= N) continue;
            const float bv = bias ? bias[ncol] : 0.f;
            const float b2vv = (MODE == 4) ? bias2[ncol] : 0.f;
            const int mbase = bm + wr * 32 + mi * 16 + lg * 4;
            #pragma unroll
            for (int r = 0; r < 4; ++r) {
                const int m = mbase + r;
                if (m >= M) continue;
                const size_t cb = (size_t)m * N + ncol;
                float v = acc[mi][ni][r];
                if (MODE == 0)      v += bv;
                else if (MODE == 3) v += bf2f(Ch[cb]) + bf2f(Cl[cb]) + bv;
                else                v = gelu_af(v + degf[m] * b2vv + bv);
                if (CSPLIT == 1) {
                    unsigned short hi = f2bf(v);
                    unsigned short lo = f2bf(v - bf2f(hi));
                    Ch[cb] = hi; Cl[cb] = lo;
                } else if (CSPLIT == 2) {
                    Ch[cb] = f2bf(v);
                } else {
                    C[cb] = v;
                }
            }
        }
    }
}

// ---------------- CSR build (counting sort by destination), batched ---------
__global__ void hist2_k(const int* __restrict__ ei, int* __restrict__ cnt) {
    int i = blockIdx.x * blockDim.x + threadIdx.x;
    if (i < NB * NE) {
        const int g = i / NE, e = i - g * NE;
        atomicAdd(&cnt[g * NN + ei[(size_t)g * NE * 2 + 2 * e + 1]], 1);
    }
}

__global__ void scan2_k(const int* __restrict__ cnt_all, int* __restrict__ row_ptr_all,
                        int* __restrict__ cursor_all, float* __restrict__ degf_all) {
    const int g = blockIdx.x;
    const int* cnt = cnt_all + g * NN;
    int* row_ptr = row_ptr_all + g * (NN + 1);
    int* cursor  = cursor_all + g * NN;
    float* degf  = degf_all + g * NN;
    __shared__ int part[256];
    int tid = threadIdx.x;
    const int per = (NN + 255) >> 8;
    int s0 = tid * per;
    int s1 = s0 + per; if (s1 > NN) s1 = NN; if (s0 > NN) s0 = NN;
    int sum = 0;
    for (int i = s0; i < s1; ++i) sum += cnt[i];
    part[tid] = sum;
    __syncthreads();
    if (tid == 0) {
        int r = 0;
        for (int i = 0; i < 256; ++i) { int v = part[i]; part[i] = r; r += v; }
    }
    __syncthreads();
    int off = part[tid];
    for (int i = s0; i < s1; ++i) {
        int c = cnt[i];
        row_ptr[i] = off; cursor[i] = off; degf[i] = (float)c;
        off += c;
    }
    if (tid == 255) row_ptr[NN] = off;
}

__global__ void fill2_k(const int* __restrict__ ei, int* __restrict__ cursor,
                        int2* __restrict__ csr_pack) {
    int i = blockIdx.x * blockDim.x + threadIdx.x;
    if (i < NB * NE) {
        const int g = i / NE, e = i - g * NE;
        const int* eig = ei + (size_t)g * NE * 2;
        int s = eig[2 * e + 0];
        int d = eig[2 * e + 1];
        int pos = atomicAdd(&cursor[g * NN + d], 1);
        csr_pack[(size_t)g * NE + pos] = make_int2(s, e);
    }
}

// ---------------- Edge aggregation v11: R13 structure + chunk prefetch ------
// 2-wave blocks, CHUNK=16, zero barriers (R13-proven) + software pipeline of
// the per-chunk csr_pack -> efeat dependent load chain (hidden under the
// current chunk's MFMA + consume phases).
__global__ __launch_bounds__(128) void edge_agg11_k(
    const unsigned short* __restrict__ T12b,  // [g][NN][512] bf16
    const float* __restrict__ efeat,
    const unsigned short* __restrict__ w1t,   // [256][544] bf16, W1c at col 512
    const int2* __restrict__ csr_pack, const int* __restrict__ row_ptr,
    unsigned short* __restrict__ Shi)
{
    __shared__ unsigned short efo[2][CHUNK * 260];   // 16640 B total

    const int tid = threadIdx.x;
    const int g   = blockIdx.x / (NN / 2);
    const int blk = blockIdx.x % (NN / 2);
    const int wave = tid >> 6, lane = tid & 63;
    const int lrow = lane & 15, lg = lane >> 4;
    const int d = blk * 2 + wave;

    const unsigned short* T12g = T12b + (size_t)g * NN * 512;
    const float* efg  = efeat + (size_t)g * NE * EDIM;
    const int2* cpG   = csr_pack + (size_t)g * NE;
    const int* rpG    = row_ptr + (size_t)g * (NN + 1);

    const int dstart = rpG[d], dend = rpG[d + 1];
    const int c0 = lane * 4;
    const char* tb = (const char*)T12g;   // row stride 1024B (512 bf16)

    // W1c^T B-fragments in registers: tile ni covers cols ni*16+lrow
    short8 bfrag[16];
    #pragma unroll
    for (int ni = 0; ni < 16; ++ni)
        bfrag[ni] = *(const short8*)&w1t[(size_t)(ni * 16 + lrow) * 544 + 512 + lg * 8];

    const ushort4 hdu = *(const ushort4*)(tb + (unsigned)d * 1024u + 512u + (unsigned)c0 * 2u);
    const float4 hd = make_float4(bf2f(hdu.x), bf2f(hdu.y), bf2f(hdu.z), bf2f(hdu.w));
    float4 acc = make_float4(0.f, 0.f, 0.f, 0.f);
    unsigned short* efw = &efo[wave][0];

    // prologue prefetch: first chunk's (src,eid) and efeat row
    int2 cp = make_int2(0, 0);
    float4 v0 = make_float4(0.f, 0.f, 0.f, 0.f), v1 = v0;
    if (dstart < dend) {
        int pos = dstart + lrow; if (pos >= dend) pos = dend - 1;
        cp = cpG[pos];
        const float* er = &efg[(size_t)cp.y * EDIM + lg * 8];
        v0 = *(const float4*)er;
        v1 = *(const float4*)(er + 4);
    }

    for (int P = dstart; P < dend; P += CHUNK) {
        const int nv = dend - P < CHUNK ? dend - P : CHUNK;
        const int myid = cp.x;   // current chunk's src id (lane = position)

        // build A fragment from prefetched efeat row
        short8 af;
        af[0] = (short)f2bf(v0.x); af[1] = (short)f2bf(v0.y);
        af[2] = (short)f2bf(v0.z); af[3] = (short)f2bf(v0.w);
        af[4] = (short)f2bf(v1.x); af[5] = (short)f2bf(v1.y);
        af[6] = (short)f2bf(v1.z); af[7] = (short)f2bf(v1.w);

        // issue next chunk's prefetch (wave-uniform branch); its latency hides
        // under this chunk's MFMA + consume
        int2 cp_n = cp; float4 w0 = v0, w1 = v1;
        if (P + CHUNK < dend) {
            int pn = P + CHUNK + lrow; if (pn >= dend) pn = dend - 1;
            cp_n = cpG[pn];
            const float* ern = &efg[(size_t)cp_n.y * EDIM + lg * 8];
            w0 = *(const float4*)ern;
            w1 = *(const float4*)(ern + 4);
        }

        // 16 MFMAs -> Ef chunk in per-wave LDS (D: row=4lg+r, col=ni*16+lrow)
        #pragma unroll
        for (int ni = 0; ni < 16; ++ni) {
            f32x4 a4 = (f32x4){0.f, 0.f, 0.f, 0.f};
            a4 = __builtin_amdgcn_mfma_f32_16x16x32_bf16(af, bfrag[ni], a4, 0, 0, 0);
            #pragma unroll
            for (int r = 0; r < 4; ++r)
                efw[(4 * lg + r) * 260 + ni * 16 + lrow] = f2bf(a4[r]);
        }

        // consume nv positions, 4-wide gather ILP (same-wave LDS, no barrier)
        for (int p = P; p < P + nv; p += 4) {
            const int nc = P + nv - p;
            int sj[4]; ushort4 hsu[4]; ushort4 ef4[4];
            #pragma unroll
            for (int j = 0; j < 4; ++j) {
                const int q = p + ((j < nc) ? j : 0);
                sj[j] = __shfl(myid, q - P, 64);
            }
            #pragma unroll
            for (int j = 0; j < 4; ++j) {
                const int q = p + ((j < nc) ? j : 0);
                hsu[j] = *(const ushort4*)(tb + (unsigned)sj[j] * 1024u + (unsigned)c0 * 2u);
                ef4[j] = *(const ushort4*)&efw[(q - P) * 260 + c0];
            }
            #pragma unroll
            for (int j = 0; j < 4; ++j) {
                if (j < nc) {   // wave-uniform predicate
                    acc.x += gelu_af(bf2f(hsu[j].x) + hd.x + bf2f(ef4[j].x));
                    acc.y += gelu_af(bf2f(hsu[j].y) + hd.y + bf2f(ef4[j].y));
                    acc.z += gelu_af(bf2f(hsu[j].z) + hd.z + bf2f(ef4[j].z));
                    acc.w += gelu_af(bf2f(hsu[j].w) + hd.w + bf2f(ef4[j].w));
                }
            }
        }

        cp = cp_n; v0 = w0; v1 = w1;   // rotate pipeline
    }

    ushort4 ho;
    ho.x = f2bf(acc.x); ho.y = f2bf(acc.y);
    ho.z = f2bf(acc.z); ho.w = f2bf(acc.w);
    *(ushort4*)&Shi[((size_t)g * NN + d) * HDIM + c0] = ho;
}

// ---------------- launcher ---------------------------------------------------
extern "C" void kernel_launch(void* const* d_in, const int* in_sizes, int n_in,
                              void* d_out, int out_size, void* d_ws, size_t ws_size,
                              hipStream_t stream)
{
    const float* nf    = (const float*)d_in[0];
    const int*   ei    = (const int*)  d_in[1];
    const float* efeat = (const float*)d_in[2];
    const float* inW   = (const float*)d_in[3];
    const float* inb   = (const float*)d_in[4];
    const float* mW1   = (const float*)d_in[5];
    const float* mb1   = (const float*)d_in[6];
    const float* mW2   = (const float*)d_in[7];
    const float* mb2   = (const float*)d_in[8];
    const float* uW1   = (const float*)d_in[9];
    const float* ub1   = (const float*)d_in[10];
    const float* uW2   = (const float*)d_in[11];
    const float* ub2   = (const float*)d_in[12];
    const float* outW  = (const float*)d_in[13];
    const float* outb  = (const float*)d_in[14];
    float* outp = (float*)d_out;

    const int MT = NB * NN;   // 40000 batched rows

    char* p = (char*)d_ws;
    auto carve = [&](size_t bytes) -> void* {
        void* r = (void*)p;
        p += (bytes + 255) & ~(size_t)255;
        return r;
    };
    unsigned short* hS  = (unsigned short*)carve((size_t)2 * MT * HDIM * 2);  // hi|lo planes
    unsigned short* T3S = (unsigned short*)carve((size_t)MT * HDIM * 2);      // Sagg single bf16
    unsigned short* T12b = (unsigned short*)carve((size_t)MT * 512 * 2);  // Hs|Hd bf16 (41 MB)
    unsigned short* US = T12b;              // alias: U (single plane) reuses dead T12
    int2* csr_pack = (int2*)carve((size_t)NB * NE * 8);
    int* row_ptr = (int*)carve((size_t)NB * (NN + 1) * 4);
    int* cursor  = (int*)carve((size_t)NB * NN * 4);
    int* cnt     = (int*)carve((size_t)NB * NN * 4);
    float* degf  = (float*)carve((size_t)MT * 4);
    unsigned short* wtbuf  = (unsigned short*)carve((size_t)1638400 * 2);
    unsigned short* w2v1bT = (unsigned short*)carve((size_t)4 * 65536 * 2);
    float* b2v     = (float*)carve((size_t)4 * 256 * 4);
    float* bias512 = (float*)carve((size_t)4 * 512 * 4);
    (void)ws_size; (void)in_sizes; (void)n_in; (void)out_size;

    unsigned short* hHi  = hS;   unsigned short* hLo  = hS  + (size_t)MT * HDIM;
    unsigned short* t3S  = T3S;  // single plane
    unsigned short* uS   = US;   // single plane

    const dim3 blk(256);
    const dim3 gIn(625, 2), gHsHd(625, 4), gU(625, 2), gRes(625, 2), gOut(625, 1);
    const dim3 gE(NB * NN / 2);   // 20000 two-wave blocks, both graphs
    const dim3 blkE(128);

    // once: weight transforms
    tr_k<<<dim3(17, 8, 18), blk, 0, stream>>>(inW, mW1, mW2, uW1, uW2, outW, wtbuf);
    wv_k<<<dim3(16, 16, 4), blk, 0, stream>>>(mW2, uW1, w2v1bT);
    bv_k<<<dim3(4), dim3(512), 0, stream>>>(mb1, mb2, uW1, b2v, bias512);

    const unsigned short* wtIn  = wtbuf;
    const unsigned short* wtW1  = wtbuf + 16384;
    const unsigned short* wtU1  = wtbuf + 835584;
    const unsigned short* wtU2  = wtbuf + 1359872;
    const unsigned short* wtOut = wtbuf + 1622016;

    // CSR for both graphs (batched)
    hipMemsetAsync(cnt, 0, (size_t)NB * NN * sizeof(int), stream);
    hist2_k<<<(NB * NE + 255) / 256, blk, 0, stream>>>(ei, cnt);
    scan2_k<<<dim3(NB), blk, 0, stream>>>(cnt, row_ptr, cursor, degf);
    fill2_k<<<(NB * NE + 255) / 256, blk, 0, stream>>>(ei, cursor, csr_pack);

    // h = nf @ in_W + in_b  (batched M=40000) -> split planes
    mgemm_k<0, 0, 1><<<gIn, blk, 0, stream>>>(
        nf, nullptr, nullptr, wtIn, NDIM,
        nullptr, nullptr, nullptr, 0,
        inb, nullptr, nullptr,
        nullptr, hHi, hLo, MT, HDIM, NDIM, 0, 0);

    for (int l = 0; l < NL; ++l) {
        const unsigned short* w1t = wtW1 + (size_t)l * 139264;
        const unsigned short* u1t = wtU1 + (size_t)l * 131072;
        const unsigned short* u2t = wtU2 + (size_t)l * 65536;

        // T12 = bf16(hHi @ [W1a|W1b] + [0,b1])   (single-plane A, 1 MFMA/frag)
        mgemm_k<0, 2, 2><<<gHsHd, blk, 0, stream>>>(
            nullptr, hHi, nullptr, w1t, 544,
            nullptr, nullptr, nullptr, 0,
            bias512 + l * 512, nullptr, nullptr,
            nullptr, T12b, nullptr, MT, 512, HDIM, 0, 256);

        // Sagg (fused Ef MFMA + aggregate, both graphs) -> t3S single bf16
        edge_agg11_k<<<gE, blkE, 0, stream>>>(T12b, efeat, w1t,
                                              csr_pack, row_ptr, t3S);

        // U = gelu(hHi@V1a + Sagg@(W2@V1b) + deg*(b2@V1b) + c1) -> uS single bf16
        mgemm_k<4, 2, 2><<<gU, blk, 0, stream>>>(
            nullptr, hHi, nullptr, u1t, 512,
            t3S, nullptr, w2v1bT + (size_t)l * 65536, 256,
            ub1 + l * HDIM, b2v + l * 256, degf,
            nullptr, uS, nullptr, MT, HDIM, HDIM, HDIM, 0);

        // h = h + U@V2 + c2  (U single plane, 1 MFMA/frag) -> split planes
        mgemm_k<3, 2, 1><<<gRes, blk, 0, stream>>>(
            nullptr, uS, nullptr, u2t, HDIM,
            nullptr, nullptr, nullptr, 0,
            ub2 + l * HDIM, nullptr, nullptr,
            nullptr, hHi, hLo, MT, HDIM, HDIM, 0, 0);
    }

    // out = h @ out_W + out_b (f32, batched; split A for final accuracy)
    mgemm_k<0, 1, 0><<<gOut, blk, 0, stream>>>(
        nullptr, hHi, hLo, wtOut, HDIM,
        nullptr, nullptr, nullptr, 0,
        outb, nullptr, nullptr,
        outp, nullptr, nullptr, MT, NDIM, HDIM, 0, 0);
}

// Round 16
// 1114.378 us; speedup vs baseline: 1.1280x; 1.0672x over previous
//
#include <hip/hip_runtime.h>

#define NN 20000     // nodes per graph
#define NE 320000    // edges per graph
#define NB 2         // graphs
#define HDIM 256     // hidden
#define NDIM 64      // node feature dim
#define EDIM 32      // edge feature dim
#define NL 4         // layers
#define CHUNK 16     // positions per edge-agg inner chunk (R8/R11/R13-proven)

typedef short short8 __attribute__((ext_vector_type(8)));
typedef float f32x4 __attribute__((ext_vector_type(4)));

// gelu(x) = x - x/(e+1),  e = exp2(2.3022082*(x+0.044715x^3))
__device__ __forceinline__ float gelu_af(float x) {
    float x3 = x * x * x;
    float e = exp2f(2.3022082f * fmaf(0.044715f, x3, x));
    return fmaf(-x, __builtin_amdgcn_rcpf(e + 1.0f), x);
}

__device__ __forceinline__ unsigned short f2bf(float f) {
    unsigned int x = __float_as_uint(f);
    unsigned int r = (x + 0x7fffu + ((x >> 16) & 1u)) >> 16;
    return (unsigned short)r;
}
__device__ __forceinline__ float bf2f(unsigned short h) {
    return __uint_as_float(((unsigned int)h) << 16);
}

// ---------------- weight transpose + bf16 convert (once per launch) ---------
__global__ __launch_bounds__(256) void tr_k(
    const float* __restrict__ inW, const float* __restrict__ mW1,
    const float* __restrict__ mW2, const float* __restrict__ uW1,
    const float* __restrict__ uW2, const float* __restrict__ outW,
    unsigned short* __restrict__ dst)
{
    const int id = blockIdx.z;
    const float* src; int K, N; size_t doff;
    if (id == 0)       { src = inW;  K = 64;  N = 256; doff = 0; }
    else if (id <= 4)  { int l = id - 1;  src = mW1 + (size_t)l * 544 * 256; K = 544; N = 256; doff = 16384   + (size_t)l * 139264; }
    else if (id <= 8)  { int l = id - 5;  src = mW2 + (size_t)l * 256 * 256; K = 256; N = 256; doff = 573440  + (size_t)l * 65536;  }
    else if (id <= 12) { int l = id - 9;  src = uW1 + (size_t)l * 512 * 256; K = 512; N = 256; doff = 835584  + (size_t)l * 131072; }
    else if (id <= 16) { int l = id - 13; src = uW2 + (size_t)l * 256 * 256; K = 256; N = 256; doff = 1359872 + (size_t)l * 65536;  }
    else               { src = outW; K = 256; N = 64;  doff = 1622016; }

    const int k0 = blockIdx.x * 32, n0 = blockIdx.y * 32;
    if (k0 >= K || n0 >= N) return;   // block-uniform

    __shared__ float tile[32][33];
    const int tx = threadIdx.x & 31, ty = threadIdx.x >> 5;
    #pragma unroll
    for (int i = 0; i < 4; ++i) {
        int k = k0 + ty + i * 8, n = n0 + tx;
        tile[ty + i * 8][tx] = (k < K && n < N) ? src[(size_t)k * N + n] : 0.f;
    }
    __syncthreads();
    #pragma unroll
    for (int i = 0; i < 4; ++i) {
        int n = n0 + ty + i * 8, k = k0 + tx;
        if (n < N && k < K) dst[doff + (size_t)n * K + k] = f2bf(tile[tx][ty + i * 8]);
    }
}

// ---------------- W2@V1b precompute: WT[n][k] = sum_j W2[k][j] V1b[j][n] ----
__global__ __launch_bounds__(256) void wv_k(
    const float* __restrict__ mW2, const float* __restrict__ uW1,
    unsigned short* __restrict__ w2v1bT)
{
    const int l = blockIdx.z;
    const float* W2  = mW2 + (size_t)l * 65536;
    const float* V1b = uW1 + (size_t)l * 131072 + 65536;
    const int n0 = blockIdx.x * 16, k0 = blockIdx.y * 16;
    const int tx = threadIdx.x & 15, ty = threadIdx.x >> 4;
    __shared__ float sW[16][17], sV[16][17];
    float acc = 0.f;
    for (int j0 = 0; j0 < 256; j0 += 16) {
        sW[ty][tx] = W2[(size_t)(k0 + ty) * 256 + j0 + tx];
        sV[ty][tx] = V1b[(size_t)(j0 + ty) * 256 + n0 + tx];
        __syncthreads();
        #pragma unroll
        for (int jj = 0; jj < 16; ++jj)
            acc = fmaf(sW[ty][jj], sV[jj][tx], acc);
        __syncthreads();
    }
    w2v1bT[(size_t)l * 65536 + (size_t)(n0 + tx) * 256 + (k0 + ty)] = f2bf(acc);
}

// ---------------- b2@V1b + fused bias512 build ------------------------------
__global__ void bv_k(const float* __restrict__ mb1, const float* __restrict__ mb2,
                     const float* __restrict__ uW1,
                     float* __restrict__ b2v, float* __restrict__ bias512)
{
    const int l = blockIdx.x, t = threadIdx.x;   // 512 threads
    if (t < 256) {
        const float* V1b = uW1 + (size_t)l * 131072 + 65536;
        const float* b2  = mb2 + l * 256;
        float s = 0.f;
        for (int j = 0; j < 256; ++j) s = fmaf(b2[j], V1b[(size_t)j * 256 + t], s);
        b2v[l * 256 + t] = s;
    }
    bias512[l * 512 + t] = (t < 256) ? 0.f : mb1[l * 256 + (t - 256)];
}

// ---------------- MFMA GEMM ------------------------------------------------
// ASPLIT=0: A f32, runtime split (2 MFMA).  ASPLIT=1: pre-split planes (2 MFMA).
// ASPLIT=2: A (and A2) single bf16 plane (1 MFMA per fragment).
// CSPLIT=0: C f32.  CSPLIT=1: C hi/lo planes.  CSPLIT=2: C bf16 single.
// MODE 0: C = A@W + bias(optional)
// MODE 3: C = (Chi+Clo) + A@W + bias      (residual; A != C buffers)
// MODE 4: C = gelu(A@W + A2@W2 + degf[m]*bias2 + bias)
template <int MODE, int ASPLIT, int CSPLIT>
__global__ __launch_bounds__(256) void mgemm_k(
    const float* __restrict__ A,
    const unsigned short* __restrict__ Ah, const unsigned short* __restrict__ Al,
    const unsigned short* __restrict__ BT, int ldb,
    const unsigned short* __restrict__ A2h, const unsigned short* __restrict__ A2l,
    const unsigned short* __restrict__ BT2, int ldb2,
    const float* __restrict__ bias, const float* __restrict__ bias2,
    const float* __restrict__ degf,
    float* __restrict__ C, unsigned short* __restrict__ Ch, unsigned short* __restrict__ Cl,
    int M, int N, int K, int K2, int bkoff)
{
    __shared__ unsigned char smem[64 * 80 * 2 + 128 * 80];  // ahi, alo, bt (80B rows)
    unsigned char* ahi = smem;
    unsigned char* alo = smem + 64 * 80;
    unsigned char* btl = smem + 64 * 80 * 2;

    const int tid = threadIdx.x;
    const int bm = blockIdx.x * 64;
    const int bn = blockIdx.y * 128;
    const int w = tid >> 6, lane = tid & 63;
    const int wr = w >> 1, wc = w & 1;
    const int lrow = lane & 15, lg = lane >> 4;

    f32x4 acc[2][4];
    #pragma unroll
    for (int i = 0; i < 2; ++i)
        #pragma unroll
        for (int j = 0; j < 4; ++j) acc[i][j] = (f32x4){0.f, 0.f, 0.f, 0.f};

    const int t1 = K >> 5, t2 = K2 >> 5;
    for (int t = 0; t < t1 + t2; ++t) {
        int k0, lda, ldbv;
        const float* Ap; const unsigned short* Ahp; const unsigned short* Alp;
        const unsigned short* Bp;
        if (t < t1) { Ap = A;  Ahp = Ah;  Alp = Al;  Bp = BT;  k0 = t * 32;        lda = K;  ldbv = ldb;  }
        else        { Ap = nullptr; Ahp = A2h; Alp = A2l; Bp = BT2; k0 = (t - t1) * 32; lda = K2; ldbv = ldb2; }

        {   // stage A
            const int row = tid >> 2, kq = (tid & 3) * 8;
            const int m = bm + row;
            if (ASPLIT == 1) {
                uint4 hv = make_uint4(0u, 0u, 0u, 0u), lv = hv;
                if (m < M) {
                    hv = *(const uint4*)&Ahp[(size_t)m * lda + k0 + kq];
                    lv = *(const uint4*)&Alp[(size_t)m * lda + k0 + kq];
                }
                *(uint4*)(ahi + row * 80 + kq * 2) = hv;
                *(uint4*)(alo + row * 80 + kq * 2) = lv;
            } else if (ASPLIT == 2) {
                uint4 hv = make_uint4(0u, 0u, 0u, 0u);
                if (m < M) hv = *(const uint4*)&Ahp[(size_t)m * lda + k0 + kq];
                *(uint4*)(ahi + row * 80 + kq * 2) = hv;
            } else {
                float4 v0 = make_float4(0.f, 0.f, 0.f, 0.f), v1 = v0;
                if (m < M) {
                    v0 = *(const float4*)&Ap[(size_t)m * lda + k0 + kq];
                    v1 = *(const float4*)&Ap[(size_t)m * lda + k0 + kq + 4];
                }
                float vv[8] = {v0.x, v0.y, v0.z, v0.w, v1.x, v1.y, v1.z, v1.w};
                unsigned short hh[8], ll[8];
                #pragma unroll
                for (int j = 0; j < 8; ++j) {
                    hh[j] = f2bf(vv[j]);
                    ll[j] = f2bf(vv[j] - bf2f(hh[j]));
                }
                ushort4 ph0 = {hh[0], hh[1], hh[2], hh[3]}, ph1 = {hh[4], hh[5], hh[6], hh[7]};
                ushort4 pl0 = {ll[0], ll[1], ll[2], ll[3]}, pl1 = {ll[4], ll[5], ll[6], ll[7]};
                *(ushort4*)(ahi + row * 80 + kq * 2)     = ph0;
                *(ushort4*)(ahi + row * 80 + kq * 2 + 8) = ph1;
                *(ushort4*)(alo + row * 80 + kq * 2)     = pl0;
                *(ushort4*)(alo + row * 80 + kq * 2 + 8) = pl1;
            }
        }
        {   // stage B: 128 n-rows x 32 k bf16; fused-B via (n>>8)*bkoff column shift
            const int row = tid >> 1, half = tid & 1;
            const int n = bn + row;
            const unsigned short* brow = Bp + (size_t)(n & 255) * ldbv + (n >> 8) * bkoff;
            #pragma unroll
            for (int c = 0; c < 2; ++c) {
                const int q = half * 2 + c;
                uint4 d = make_uint4(0u, 0u, 0u, 0u);
                if (n < N) d = *(const uint4*)&brow[k0 + q * 8];
                *(uint4*)(btl + row * 80 + q * 16) = d;
            }
        }
        __syncthreads();

        short8 ah[2], al[2], bfr[4];
        #pragma unroll
        for (int mi = 0; mi < 2; ++mi) {
            const int r = wr * 32 + mi * 16 + lrow;
            ah[mi] = *(const short8*)(ahi + r * 80 + lg * 16);
            if (ASPLIT != 2) al[mi] = *(const short8*)(alo + r * 80 + lg * 16);
        }
        #pragma unroll
        for (int ni = 0; ni < 4; ++ni) {
            const int r = wc * 64 + ni * 16 + lrow;
            bfr[ni] = *(const short8*)(btl + r * 80 + lg * 16);
        }
        #pragma unroll
        for (int mi = 0; mi < 2; ++mi)
            #pragma unroll
            for (int ni = 0; ni < 4; ++ni) {
                acc[mi][ni] = __builtin_amdgcn_mfma_f32_16x16x32_bf16(ah[mi], bfr[ni], acc[mi][ni], 0, 0, 0);
                if (ASPLIT != 2)
                    acc[mi][ni] = __builtin_amdgcn_mfma_f32_16x16x32_bf16(al[mi], bfr[ni], acc[mi][ni], 0, 0, 0);
            }
        __syncthreads();
    }

    // epilogue: D row = 4*lg + reg, col = lrow
    #pragma unroll
    for (int mi = 0; mi < 2; ++mi) {
        #pragma unroll
        for (int ni = 0; ni < 4; ++ni) {
            const int ncol = bn + wc * 64 + ni * 16 + lrow;
            if (ncol >= N) continue;
            const float bv = bias ? bias[ncol] : 0.f;
            const float b2vv = (MODE == 4) ? bias2[ncol] : 0.f;
            const int mbase = bm + wr * 32 + mi * 16 + lg * 4;
            #pragma unroll
            for (int r = 0; r < 4; ++r) {
                const int m = mbase + r;
                if (m >= M) continue;
                const size_t cb = (size_t)m * N + ncol;
                float v = acc[mi][ni][r];
                if (MODE == 0)      v += bv;
                else if (MODE == 3) v += bf2f(Ch[cb]) + bf2f(Cl[cb]) + bv;
                else                v = gelu_af(v + degf[m] * b2vv + bv);
                if (CSPLIT == 1) {
                    unsigned short hi = f2bf(v);
                    unsigned short lo = f2bf(v - bf2f(hi));
                    Ch[cb] = hi; Cl[cb] = lo;
                } else if (CSPLIT == 2) {
                    Ch[cb] = f2bf(v);
                } else {
                    C[cb] = v;
                }
            }
        }
    }
}

// ---------------- CSR build (counting sort by destination), batched ---------
__global__ void hist2_k(const int* __restrict__ ei, int* __restrict__ cnt) {
    int i = blockIdx.x * blockDim.x + threadIdx.x;
    if (i < NB * NE) {
        const int g = i / NE, e = i - g * NE;
        atomicAdd(&cnt[g * NN + ei[(size_t)g * NE * 2 + 2 * e + 1]], 1);
    }
}

__global__ void scan2_k(const int* __restrict__ cnt_all, int* __restrict__ row_ptr_all,
                        int* __restrict__ cursor_all, float* __restrict__ degf_all) {
    const int g = blockIdx.x;
    const int* cnt = cnt_all + g * NN;
    int* row_ptr = row_ptr_all + g * (NN + 1);
    int* cursor  = cursor_all + g * NN;
    float* degf  = degf_all + g * NN;
    __shared__ int part[256];
    int tid = threadIdx.x;
    const int per = (NN + 255) >> 8;
    int s0 = tid * per;
    int s1 = s0 + per; if (s1 > NN) s1 = NN; if (s0 > NN) s0 = NN;
    int sum = 0;
    for (int i = s0; i < s1; ++i) sum += cnt[i];
    part[tid] = sum;
    __syncthreads();
    if (tid == 0) {
        int r = 0;
        for (int i = 0; i < 256; ++i) { int v = part[i]; part[i] = r; r += v; }
    }
    __syncthreads();
    int off = part[tid];
    for (int i = s0; i < s1; ++i) {
        int c = cnt[i];
        row_ptr[i] = off; cursor[i] = off; degf[i] = (float)c;
        off += c;
    }
    if (tid == 255) row_ptr[NN] = off;
}

__global__ void fill2_k(const int* __restrict__ ei, int* __restrict__ cursor,
                        int2* __restrict__ csr_pack) {
    int i = blockIdx.x * blockDim.x + threadIdx.x;
    if (i < NB * NE) {
        const int g = i / NE, e = i - g * NE;
        const int* eig = ei + (size_t)g * NE * 2;
        int s = eig[2 * e + 0];
        int d = eig[2 * e + 1];
        int pos = atomicAdd(&cursor[g * NN + d], 1);
        csr_pack[(size_t)g * NE + pos] = make_int2(s, e);
    }
}

// ---------------- Edge aggregation v12: R13 structure + csr-only prefetch ---
// 2-wave blocks, CHUNK=16, zero barriers (R13-proven). Only the int2 csr_pack
// entry for the next chunk is prefetched (+2 VGPR) — breaks the two-deep
// csr->efeat serial chain at chunk head without R15's register-pressure cost.
__global__ __launch_bounds__(128) void edge_agg12_k(
    const unsigned short* __restrict__ T12b,  // [g][NN][512] bf16
    const float* __restrict__ efeat,
    const unsigned short* __restrict__ w1t,   // [256][544] bf16, W1c at col 512
    const int2* __restrict__ csr_pack, const int* __restrict__ row_ptr,
    unsigned short* __restrict__ Shi)
{
    __shared__ unsigned short efo[2][CHUNK * 260];   // 16640 B total

    const int tid = threadIdx.x;
    const int g   = blockIdx.x / (NN / 2);
    const int blk = blockIdx.x % (NN / 2);
    const int wave = tid >> 6, lane = tid & 63;
    const int lrow = lane & 15, lg = lane >> 4;
    const int d = blk * 2 + wave;

    const unsigned short* T12g = T12b + (size_t)g * NN * 512;
    const float* efg  = efeat + (size_t)g * NE * EDIM;
    const int2* cpG   = csr_pack + (size_t)g * NE;
    const int* rpG    = row_ptr + (size_t)g * (NN + 1);

    const int dstart = rpG[d], dend = rpG[d + 1];
    const int c0 = lane * 4;
    const char* tb = (const char*)T12g;   // row stride 1024B (512 bf16)

    // W1c^T B-fragments in registers: tile ni covers cols ni*16+lrow
    short8 bfrag[16];
    #pragma unroll
    for (int ni = 0; ni < 16; ++ni)
        bfrag[ni] = *(const short8*)&w1t[(size_t)(ni * 16 + lrow) * 544 + 512 + lg * 8];

    const ushort4 hdu = *(const ushort4*)(tb + (unsigned)d * 1024u + 512u + (unsigned)c0 * 2u);
    const float4 hd = make_float4(bf2f(hdu.x), bf2f(hdu.y), bf2f(hdu.z), bf2f(hdu.w));
    float4 acc = make_float4(0.f, 0.f, 0.f, 0.f);
    unsigned short* efw = &efo[wave][0];

    // prologue: first chunk's (src,eid)
    int2 cp = make_int2(0, 0);
    if (dstart < dend) {
        int pos = dstart + lrow; if (pos >= dend) pos = dend - 1;
        cp = cpG[pos];
    }

    for (int P = dstart; P < dend; P += CHUNK) {
        const int nv = dend - P < CHUNK ? dend - P : CHUNK;
        const int myid = cp.x, eid = cp.y;

        // efeat row load can issue immediately (cp already resident)
        const float* er = &efg[(size_t)eid * EDIM + lg * 8];
        float4 v0 = *(const float4*)er;
        float4 v1 = *(const float4*)(er + 4);

        // prefetch next chunk's csr entry (wave-uniform branch, +2 VGPR)
        int2 cp_n = cp;
        if (P + CHUNK < dend) {
            int pn = P + CHUNK + lrow; if (pn >= dend) pn = dend - 1;
            cp_n = cpG[pn];
        }

        short8 af;
        af[0] = (short)f2bf(v0.x); af[1] = (short)f2bf(v0.y);
        af[2] = (short)f2bf(v0.z); af[3] = (short)f2bf(v0.w);
        af[4] = (short)f2bf(v1.x); af[5] = (short)f2bf(v1.y);
        af[6] = (short)f2bf(v1.z); af[7] = (short)f2bf(v1.w);

        // 16 MFMAs -> Ef chunk in per-wave LDS (D: row=4lg+r, col=ni*16+lrow)
        #pragma unroll
        for (int ni = 0; ni < 16; ++ni) {
            f32x4 a4 = (f32x4){0.f, 0.f, 0.f, 0.f};
            a4 = __builtin_amdgcn_mfma_f32_16x16x32_bf16(af, bfrag[ni], a4, 0, 0, 0);
            #pragma unroll
            for (int r = 0; r < 4; ++r)
                efw[(4 * lg + r) * 260 + ni * 16 + lrow] = f2bf(a4[r]);
        }

        // consume nv positions, 4-wide gather ILP (same-wave LDS, no barrier)
        for (int p = P; p < P + nv; p += 4) {
            const int nc = P + nv - p;
            int sj[4]; ushort4 hsu[4]; ushort4 ef4[4];
            #pragma unroll
            for (int j = 0; j < 4; ++j) {
                const int q = p + ((j < nc) ? j : 0);
                sj[j] = __shfl(myid, q - P, 64);
            }
            #pragma unroll
            for (int j = 0; j < 4; ++j) {
                const int q = p + ((j < nc) ? j : 0);
                hsu[j] = *(const ushort4*)(tb + (unsigned)sj[j] * 1024u + (unsigned)c0 * 2u);
                ef4[j] = *(const ushort4*)&efw[(q - P) * 260 + c0];
            }
            #pragma unroll
            for (int j = 0; j < 4; ++j) {
                if (j < nc) {   // wave-uniform predicate
                    acc.x += gelu_af(bf2f(hsu[j].x) + hd.x + bf2f(ef4[j].x));
                    acc.y += gelu_af(bf2f(hsu[j].y) + hd.y + bf2f(ef4[j].y));
                    acc.z += gelu_af(bf2f(hsu[j].z) + hd.z + bf2f(ef4[j].z));
                    acc.w += gelu_af(bf2f(hsu[j].w) + hd.w + bf2f(ef4[j].w));
                }
            }
        }

        cp = cp_n;
    }

    ushort4 ho;
    ho.x = f2bf(acc.x); ho.y = f2bf(acc.y);
    ho.z = f2bf(acc.z); ho.w = f2bf(acc.w);
    *(ushort4*)&Shi[((size_t)g * NN + d) * HDIM + c0] = ho;
}

// ---------------- launcher ---------------------------------------------------
extern "C" void kernel_launch(void* const* d_in, const int* in_sizes, int n_in,
                              void* d_out, int out_size, void* d_ws, size_t ws_size,
                              hipStream_t stream)
{
    const float* nf    = (const float*)d_in[0];
    const int*   ei    = (const int*)  d_in[1];
    const float* efeat = (const float*)d_in[2];
    const float* inW   = (const float*)d_in[3];
    const float* inb   = (const float*)d_in[4];
    const float* mW1   = (const float*)d_in[5];
    const float* mb1   = (const float*)d_in[6];
    const float* mW2   = (const float*)d_in[7];
    const float* mb2   = (const float*)d_in[8];
    const float* uW1   = (const float*)d_in[9];
    const float* ub1   = (const float*)d_in[10];
    const float* uW2   = (const float*)d_in[11];
    const float* ub2   = (const float*)d_in[12];
    const float* outW  = (const float*)d_in[13];
    const float* outb  = (const float*)d_in[14];
    float* outp = (float*)d_out;

    const int MT = NB * NN;   // 40000 batched rows

    char* p = (char*)d_ws;
    auto carve = [&](size_t bytes) -> void* {
        void* r = (void*)p;
        p += (bytes + 255) & ~(size_t)255;
        return r;
    };
    unsigned short* hS  = (unsigned short*)carve((size_t)2 * MT * HDIM * 2);  // hi|lo planes
    unsigned short* T3S = (unsigned short*)carve((size_t)MT * HDIM * 2);      // Sagg single bf16
    unsigned short* T12b = (unsigned short*)carve((size_t)MT * 512 * 2);  // Hs|Hd bf16 (41 MB)
    unsigned short* US = T12b;              // alias: U (single plane) reuses dead T12
    int2* csr_pack = (int2*)carve((size_t)NB * NE * 8);
    int* row_ptr = (int*)carve((size_t)NB * (NN + 1) * 4);
    int* cursor  = (int*)carve((size_t)NB * NN * 4);
    int* cnt     = (int*)carve((size_t)NB * NN * 4);
    float* degf  = (float*)carve((size_t)MT * 4);
    unsigned short* wtbuf  = (unsigned short*)carve((size_t)1638400 * 2);
    unsigned short* w2v1bT = (unsigned short*)carve((size_t)4 * 65536 * 2);
    float* b2v     = (float*)carve((size_t)4 * 256 * 4);
    float* bias512 = (float*)carve((size_t)4 * 512 * 4);
    (void)ws_size; (void)in_sizes; (void)n_in; (void)out_size;

    unsigned short* hHi  = hS;   unsigned short* hLo  = hS  + (size_t)MT * HDIM;
    unsigned short* t3S  = T3S;  // single plane
    unsigned short* uS   = US;   // single plane

    const dim3 blk(256);
    const dim3 gIn(625, 2), gHsHd(625, 4), gU(625, 2), gRes(625, 2), gOut(625, 1);
    const dim3 gE(NB * NN / 2);   // 20000 two-wave blocks, both graphs
    const dim3 blkE(128);

    // once: weight transforms
    tr_k<<<dim3(17, 8, 18), blk, 0, stream>>>(inW, mW1, mW2, uW1, uW2, outW, wtbuf);
    wv_k<<<dim3(16, 16, 4), blk, 0, stream>>>(mW2, uW1, w2v1bT);
    bv_k<<<dim3(4), dim3(512), 0, stream>>>(mb1, mb2, uW1, b2v, bias512);

    const unsigned short* wtIn  = wtbuf;
    const unsigned short* wtW1  = wtbuf + 16384;
    const unsigned short* wtU1  = wtbuf + 835584;
    const unsigned short* wtU2  = wtbuf + 1359872;
    const unsigned short* wtOut = wtbuf + 1622016;

    // CSR for both graphs (batched)
    hipMemsetAsync(cnt, 0, (size_t)NB * NN * sizeof(int), stream);
    hist2_k<<<(NB * NE + 255) / 256, blk, 0, stream>>>(ei, cnt);
    scan2_k<<<dim3(NB), blk, 0, stream>>>(cnt, row_ptr, cursor, degf);
    fill2_k<<<(NB * NE + 255) / 256, blk, 0, stream>>>(ei, cursor, csr_pack);

    // h = nf @ in_W + in_b  (batched M=40000) -> split planes
    mgemm_k<0, 0, 1><<<gIn, blk, 0, stream>>>(
        nf, nullptr, nullptr, wtIn, NDIM,
        nullptr, nullptr, nullptr, 0,
        inb, nullptr, nullptr,
        nullptr, hHi, hLo, MT, HDIM, NDIM, 0, 0);

    for (int l = 0; l < NL; ++l) {
        const unsigned short* w1t = wtW1 + (size_t)l * 139264;
        const unsigned short* u1t = wtU1 + (size_t)l * 131072;
        const unsigned short* u2t = wtU2 + (size_t)l * 65536;

        // T12 = bf16(hHi @ [W1a|W1b] + [0,b1])   (single-plane A, 1 MFMA/frag)
        mgemm_k<0, 2, 2><<<gHsHd, blk, 0, stream>>>(
            nullptr, hHi, nullptr, w1t, 544,
            nullptr, nullptr, nullptr, 0,
            bias512 + l * 512, nullptr, nullptr,
            nullptr, T12b, nullptr, MT, 512, HDIM, 0, 256);

        // Sagg (fused Ef MFMA + aggregate, both graphs) -> t3S single bf16
        edge_agg12_k<<<gE, blkE, 0, stream>>>(T12b, efeat, w1t,
                                              csr_pack, row_ptr, t3S);

        // U = gelu(hHi@V1a + Sagg@(W2@V1b) + deg*(b2@V1b) + c1) -> uS single bf16
        mgemm_k<4, 2, 2><<<gU, blk, 0, stream>>>(
            nullptr, hHi, nullptr, u1t, 512,
            t3S, nullptr, w2v1bT + (size_t)l * 65536, 256,
            ub1 + l * HDIM, b2v + l * 256, degf,
            nullptr, uS, nullptr, MT, HDIM, HDIM, HDIM, 0);

        // h = h + U@V2 + c2  (U single plane, 1 MFMA/frag) -> split planes
        mgemm_k<3, 2, 1><<<gRes, blk, 0, stream>>>(
            nullptr, uS, nullptr, u2t, HDIM,
            nullptr, nullptr, nullptr, 0,
            ub2 + l * HDIM, nullptr, nullptr,
            nullptr, hHi, hLo, MT, HDIM, HDIM, 0, 0);
    }

    // out = h @ out_W + out_b (f32, batched; split A for final accuracy)
    mgemm_k<0, 1, 0><<<gOut, blk, 0, stream>>>(
        nullptr, hHi, hLo, wtOut, HDIM,
        nullptr, nullptr, nullptr, 0,
        outb, nullptr, nullptr,
        outp, nullptr, nullptr, MT, NDIM, HDIM, 0, 0);
}